// Round 10
// baseline (263.711 us; speedup 1.0000x reference)
//
#include <hip/hip_runtime.h>
#include <hip/hip_bf16.h>

#define B_  64
#define T_  256
#define D_  768
#define NH_ 12
#define DH_ 64
#define C_  7
#define QS_ 2304            // qkv fused row stride (3*D)

using f32x4  = __attribute__((ext_vector_type(4))) float;
using bf16x8 = __attribute__((ext_vector_type(8))) __bf16;
using u16x8  = __attribute__((ext_vector_type(8))) unsigned short;
using u16x4  = __attribute__((ext_vector_type(4))) unsigned short;
using s16x4  = __attribute__((ext_vector_type(4))) short;

#if defined(__has_builtin)
#if __has_builtin(__builtin_amdgcn_mfma_f32_16x16x16bf16_1k)
#define HAS_MFMA16 1
#endif
#endif
// NOTE: HAS_MFMA16 differs between host and device compile passes (host pass
// can't see amdgcn builtins). Launch config and kernel signatures MUST be
// identical in both branches — R3/R4 failed on exactly this.

static __device__ inline unsigned short f2bf(float f) {
    union { float f; unsigned u; } c; c.f = f;
    unsigned u = c.u;
    return (unsigned short)((u + 0x7fffu + ((u >> 16) & 1u)) >> 16);
}

// async global->LDS, 16 bytes per lane (wave-uniform LDS base + lane*16)
#define ASYNC16(gp, lp) __builtin_amdgcn_global_load_lds(                      \
    (const __attribute__((address_space(1))) unsigned int*)(gp),               \
    (__attribute__((address_space(3))) unsigned int*)(lp), 16, 0, 0)

// ---------------------------------------------------------------------------
// Fused prologue (one launch): flat grid. Slow serial blocks (Wf = Wo@Wc2)
// FIRST so they overlap the 6144 conv blocks instead of tailing.
// ---------------------------------------------------------------------------
#define PRO_WF   13
#define PRO_BIAS 9
#define PRO_TR   1728           // 3 * 576
#define PRO_CONV 6144
#define PRO_ALL  (PRO_WF + PRO_BIAS + PRO_TR + PRO_CONV)

__global__ __launch_bounds__(256) void prologue(
    const float* __restrict__ H, unsigned short* __restrict__ Hb,
    const float* __restrict__ Wq, const float* __restrict__ Wk,
    const float* __restrict__ Wv,
    unsigned short* __restrict__ Wqkvt,
    const float* __restrict__ bq, const float* __restrict__ bk,
    const float* __restrict__ bv, float* __restrict__ bqkv,
    const float* __restrict__ Wo, const float* __restrict__ Wc,
    const float* __restrict__ bo,
    float* __restrict__ Wf, float* __restrict__ boc)
{
    __shared__ float tile[32][33];
    __shared__ float wcs[D_ * C_];          // Wc2 staged f32 (21.5 KB)
    const int blk = blockIdx.x;
    const int tid = threadIdx.x;

    if (blk < PRO_WF) {
        const int fb = blk;                  // 0..12
        for (int i = tid; i < D_ * C_; i += 256)
            wcs[i] = Wc[(size_t)D_ * C_ + i];
        __syncthreads();
        if (fb < 12) {
            const int dl = tid >> 2;
            const int ks = tid & 3;
            const int d  = fb * 64 + dl;
            const float* wrow = Wo + (size_t)d * D_;
            float a[C_] = {};
            for (int e = ks * 192; e < ks * 192 + 192; ++e) {
                const float w = wrow[e];
#pragma unroll
                for (int c = 0; c < C_; ++c) a[c] += w * wcs[e * C_ + c];
            }
#pragma unroll
            for (int c = 0; c < C_; ++c) {
                a[c] += __shfl_xor(a[c], 1, 64);
                a[c] += __shfl_xor(a[c], 2, 64);
            }
            if (ks == 0) {
#pragma unroll
                for (int c = 0; c < C_; ++c) Wf[d * C_ + c] = a[c];
            }
        } else if (tid < C_) {
            float a = 0.f;
            for (int e = 0; e < D_; ++e) a += bo[e] * wcs[e * C_ + tid];
            boc[tid] = a;
        }
    } else if (blk < PRO_WF + PRO_BIAS) {
        const int i = (blk - PRO_WF) * 256 + tid;
        if (i < D_)          bqkv[i] = bq[i];
        else if (i < 2 * D_) bqkv[i] = bk[i - D_];
        else if (i < 3 * D_) bqkv[i] = bv[i - 2 * D_];
    } else if (blk < PRO_WF + PRO_BIAS + PRO_TR) {
        const int tb = blk - PRO_WF - PRO_BIAS;
        const int z = tb / 576;             // 0..2 (Wq,Wk,Wv)
        const int rem = tb - z * 576;
        const int bx = (rem % 24) * 32;
        const int by = (rem / 24) * 32;
        const size_t wsz = (size_t)D_ * D_;
        const float* W = (z == 0) ? Wq : (z == 1) ? Wk : Wv;
        unsigned short* Wt = Wqkvt + (size_t)z * wsz;
        const int tx = tid & 31;
        const int ty = tid >> 5;
#pragma unroll
        for (int i = ty; i < 32; i += 8)
            tile[i][tx] = W[(size_t)(by + i) * D_ + bx + tx];
        __syncthreads();
#pragma unroll
        for (int i = ty; i < 32; i += 8)
            Wt[(size_t)(bx + i) * D_ + by + tx] = f2bf(tile[tx][i]);
    } else {
        const int i = ((blk - PRO_WF - PRO_BIAS - PRO_TR) * 256 + tid) * 8;
        float4 f0 = *(const float4*)(H + i);
        float4 f1 = *(const float4*)(H + i + 4);
        u16x8 u;
        u[0] = f2bf(f0.x); u[1] = f2bf(f0.y); u[2] = f2bf(f0.z); u[3] = f2bf(f0.w);
        u[4] = f2bf(f1.x); u[5] = f2bf(f1.y); u[6] = f2bf(f1.z); u[7] = f2bf(f1.w);
        *(uint4*)(Hb + i) = __builtin_bit_cast(uint4, u);
    }
}

// ---------------------------------------------------------------------------
// qkv projection: 8-phase 256x256 deep-pipelined bf16 MFMA GEMM (m201 port).
//   C[16384,2304] = Hb[16384,768] @ Wqkvt[2304,768]^T + bqkv
// 512 thr, 8 waves (2M x 4N), per-wave 128x64 (acc[8][4]). LDS 128 KB 2-deep.
// Per K-tile, 4 phases (quadrants): ph1 (M0,N0), ph2 (M0,N1), ph3 (M1,N1),
// ph4 (M1,N0 — zero ds_reads, bf0 retained). Each phase stages exactly one
// half-tile (2 loads/thread) and ends {BAR; lgkm0; prio1; 16 MFMA; prio0; BAR}.
// vmcnt(6) ONLY at ph4 (3 half-tiles = 6 loads stay in flight).
//
// Region lifetimes (buf q=g&1, qn=(g+1)&1):
//   A-half0 = rows {0-63, 128-191} (both wave-groups' M0), read ph1.
//   A-half1 = rows {64-127, 192-255}, read ph3.
//   B-half0 = rows 0-127 (waves wn in {0,64}), fully read after ph2.
//   B-half1 = rows 128-255, fully read after ph2.
// Stage schedule: ph1(g): A1(g+1)->qn [prev A1(g-1) read ph3(g-1)];
//   ph2(g): A0(g+2)->q [A0(g) read ph1(g)]; ph3(g): B0(g+2)->q [B(g) read
//   <= ph2(g)]; ph4(g): B1(g+2)->q. vmcnt(6) at ph4(g) => newest 6 loads =
//   {A0,B0,B1}(g+2) may pend; A1(g+1) and older (all of tile g+1) landed.
// Dead-wave skip: BM=256 = one batch; for k/v col tiles with nt<=128, waves
// wm=128 (rows 128-255, never read downstream) skip ds_reads/MFMA/epilogue
// but keep stages+barriers (no divergent barriers).
// Swizzle: measured-conflict-free involution slot = chunk ^ (row&7), write
// side via pre-swizzled global source (verified R6/R8/R9, 0 bank conflicts).
// ---------------------------------------------------------------------------
#define QBM 256
#define QBN 256
#define QBK 64
#define KQ  768
#define NKT 12

#define BAR   do { __builtin_amdgcn_s_barrier();                               \
                   __builtin_amdgcn_sched_barrier(0); } while (0)
#define LGKM0 do { asm volatile("s_waitcnt lgkmcnt(0)" ::: "memory");          \
                   __builtin_amdgcn_sched_barrier(0); } while (0)
#define VMW(n) do { asm volatile("s_waitcnt vmcnt(" #n ")" ::: "memory");      \
                    __builtin_amdgcn_sched_barrier(0); } while (0)

__global__ __launch_bounds__(512, 2) void gemm_qkv_8ph(
    const unsigned short* __restrict__ A,    // Hb [16384][768]
    const unsigned short* __restrict__ Bt,   // Wqkvt [2304][768]
    const float* __restrict__ bias,          // bqkv [2304]
    unsigned short* __restrict__ qkvb,       // [16384][2304] (q,k cols)
    unsigned short* __restrict__ Vt,         // [bh][d][t]
    const int* __restrict__ num_turns)
{
    __shared__ unsigned short As[2][QBM * QBK];   // 64 KB
    __shared__ unsigned short Bs[2][QBN * QBK];   // 64 KB

    const int tid = threadIdx.x;
    const int wid = tid >> 6;
    const int ln  = tid & 63;
    const int hi  = ln >> 4;
    const int lo  = ln & 15;
    const int wm  = (wid >> 2) * 128;    // {0,128}
    const int wn  = (wid & 3) * 64;      // {0,64,128,192}

    // XCD remap: 576 blocks = 8 xcd * 72 contiguous tiles (bijective)
    const int L  = blockIdx.y * gridDim.x + blockIdx.x;   // grid (9,64)
    const int wg = (L & 7) * 72 + (L >> 3);
    const int my = wg / 9;
    const int nx = wg - my * 9;
    const int row0 = my * QBM;           // one full batch: b = my
    const int col0 = nx * QBN;

    const int  ntb      = num_turns[my];
    const bool deadwave = (col0 >= D_) && (wm == 128) && (ntb <= 128);

    // staging addressing: thread tid -> row s0 (of 64-row load unit),
    // pre-swizzled chunk ch; (row&7) == (s0&7) for every 64-aligned unit.
    const int s0 = tid >> 3;
    const int ch = (tid & 7) ^ (s0 & 7);
    const unsigned short* a0 = A  + (size_t)(row0 + s0) * KQ + ch * 8;
    const unsigned short* b0 = Bt + (size_t)(col0 + s0) * KQ + ch * 8;

// A half h: row-quarters {h*64, h*64+128}; B half h: rows [h*128, h*128+128)
#define STG_AH(t, q, h) do {                                                   \
    ASYNC16(a0 + (size_t)(t) * QBK + (size_t)((h) * 64) * KQ,                  \
            &As[q][(h) * 4096 + wid * 512]);                                   \
    ASYNC16(a0 + (size_t)(t) * QBK + (size_t)((h) * 64 + 128) * KQ,            \
            &As[q][(h) * 4096 + 8192 + wid * 512]);                            \
} while (0)
#define STG_BH(t, q, h) do {                                                   \
    ASYNC16(b0 + (size_t)(t) * QBK + (size_t)((h) * 128) * KQ,                 \
            &Bs[q][(h) * 8192 + wid * 512]);                                   \
    ASYNC16(b0 + (size_t)(t) * QBK + (size_t)((h) * 128 + 64) * KQ,            \
            &Bs[q][(h) * 8192 + 4096 + wid * 512]);                            \
} while (0)

    const int fcs[2] = { (0 * 4 + hi) ^ (lo & 7), (1 * 4 + hi) ^ (lo & 7) };

    f32x4  acc[8][4] = {};
    bf16x8 af[4][2];          // current M-half A frags (reused ph1/ph3)
    bf16x8 bf0[2][2];         // N cols wn+0..31  (read ph1, reused ph4)
    bf16x8 bf1[2][2];         // N cols wn+32..63 (read ph2, reused ph3)

#define RD_A(q, half) do {                                                     \
  _Pragma("unroll") for (int mf = 0; mf < 4; ++mf)                             \
  _Pragma("unroll") for (int ks = 0; ks < 2; ++ks)                             \
    af[mf][ks] = *(const bf16x8*)&As[q][(wm + (half) * 64 + mf * 16 + lo) * QBK + fcs[ks] * 8]; \
} while (0)
#define RD_B(q, dst, off) do {                                                 \
  _Pragma("unroll") for (int nf = 0; nf < 2; ++nf)                             \
  _Pragma("unroll") for (int ks = 0; ks < 2; ++ks)                             \
    dst[nf][ks] = *(const bf16x8*)&Bs[q][(wn + (off) + nf * 16 + lo) * QBK + fcs[ks] * 8]; \
} while (0)
#define MM(i0, j0, bsrc) do {                                                  \
  __builtin_amdgcn_s_setprio(1);                                               \
  _Pragma("unroll") for (int mf = 0; mf < 4; ++mf)                             \
  _Pragma("unroll") for (int nf = 0; nf < 2; ++nf)                             \
  _Pragma("unroll") for (int ks = 0; ks < 2; ++ks)                             \
    acc[(i0) + mf][(j0) + nf] = __builtin_amdgcn_mfma_f32_16x16x32_bf16(       \
        af[mf][ks], bsrc[nf][ks], acc[(i0) + mf][(j0) + nf], 0, 0, 0);         \
  __builtin_amdgcn_s_setprio(0);                                               \
} while (0)

#define GROUP(gg, q_, qn_) do {                                                \
    /* ph1: (M0,N0) */                                                         \
    if (!deadwave) { RD_A(q_, 0); RD_B(q_, bf0, 0); }                          \
    if ((gg) + 1 < NKT) STG_AH((gg) + 1, qn_, 1);                              \
    BAR; LGKM0;                                                                \
    if (!deadwave) MM(0, 0, bf0);                                              \
    BAR;                                                                       \
    /* ph2: (M0,N1) */                                                         \
    if (!deadwave) RD_B(q_, bf1, 32);                                          \
    if ((gg) + 2 < NKT) STG_AH((gg) + 2, q_, 0);                               \
    BAR; LGKM0;                                                                \
    if (!deadwave) MM(0, 2, bf1);                                              \
    BAR;                                                                       \
    /* ph3: (M1,N1) */                                                         \
    if (!deadwave) RD_A(q_, 1);                                                \
    if ((gg) + 2 < NKT) STG_BH((gg) + 2, q_, 0);                               \
    BAR; LGKM0;                                                                \
    if (!deadwave) MM(4, 2, bf1);                                              \
    BAR;                                                                       \
    /* ph4: (M1,N0), counted vmcnt */                                          \
    if ((gg) + 2 < NKT) { STG_BH((gg) + 2, q_, 1); VMW(6); }                   \
    else if ((gg) + 1 < NKT) VMW(0);                                           \
    BAR; LGKM0;                                                                \
    if (!deadwave) MM(4, 0, bf0);                                              \
    BAR;                                                                       \
} while (0)

    // pipeline prologue: tile0 complete (4 halves) + tile1 {A0,B0,B1};
    // A1(1) is staged in ph1 of group 0. vmcnt(6) => tile0's 8 loads landed.
    STG_AH(0, 0, 0); STG_BH(0, 0, 0); STG_BH(0, 0, 1); STG_AH(0, 0, 1);
    STG_AH(1, 1, 0); STG_BH(1, 1, 0); STG_BH(1, 1, 1);
    VMW(6); BAR;

#pragma unroll
    for (int g = 0; g < NKT; g += 2) {
        GROUP(g + 0, 0, 1);
        GROUP(g + 1, 1, 0);
    }
#undef STG_AH
#undef STG_BH
#undef RD_A
#undef RD_B
#undef MM
#undef GROUP

    if (deadwave) return;

    // ---- C write (verified epilogue formulas, mf extended to 8) ----
    const int t0 = row0 & (T_ - 1);      // == 0 (row0 multiple of 256)
    if (col0 >= 1536) {
        // v tile -> Vt[bh][d][t], 8B packed stores (4 consecutive t per store)
#pragma unroll
        for (int j = 0; j < 4; ++j) {
            const int dcol = (col0 - 1536) + wn + j * 16 + lo;   // [0,768)
            const float bcol = bias[col0 + wn + j * 16 + lo];
            unsigned short* vrow =
                Vt + ((size_t)(my * NH_ + (dcol >> 6)) * DH_ + (dcol & 63)) * T_ + t0;
#pragma unroll
            for (int i = 0; i < 8; ++i) {
                u16x4 pk;
#pragma unroll
                for (int r = 0; r < 4; ++r) pk[r] = f2bf(acc[i][j][r] + bcol);
                *(u16x4*)(vrow + wm + i * 16 + hi * 4) = pk;
            }
        }
        return;
    }
#pragma unroll
    for (int j = 0; j < 4; ++j) {
        const int col = col0 + wn + j * 16 + lo;
        const float bcol = bias[col];
#pragma unroll
        for (int i = 0; i < 8; ++i) {
#pragma unroll
            for (int r = 0; r < 4; ++r) {
                const int row = row0 + wm + i * 16 + hi * 4 + r;
                qkvb[(size_t)row * QS_ + col] = f2bf(acc[i][j][r] + bcol);
            }
        }
    }
}

// ---------------------------------------------------------------------------
// Fused MFMA flash attention, block-per-bh, 512 threads (8 waves x 2 balanced
// q-tiles {w, 15-w}). LAUNCH CONFIG IDENTICAL FOR BOTH COMPILE BRANCHES
// (<<<768, 512>>>). K/V staged via ASYNC global_load_lds with PRE-SWIZZLED
// per-lane global source + linear LDS dest (verified R8).
// ---------------------------------------------------------------------------
#if HAS_MFMA16
__global__ __launch_bounds__(512) void attn_fused(
    const unsigned short* __restrict__ qkv, const unsigned short* __restrict__ Vt,
    const int* __restrict__ num_turns, unsigned short* __restrict__ ctx)
{
    __shared__ unsigned short Klds[256 * 64];   // 32 KB
    __shared__ unsigned short Vlds[64 * 256];   // 32 KB (row stride vst shorts)

    const int bh = blockIdx.x;
    const int b = bh / NH_;
    const int h = bh - b * NH_;
    const int tid = threadIdx.x;
    const int wave = tid >> 6;
    const int lane = tid & 63;
    const int hi = lane >> 4;
    const int lo = lane & 15;
    const int lo7 = lo & 7;

    const int nt = num_turns[b];
    const int kend16 = (min(254, nt - 1) >> 4) + 1;   // staged K tiles (1..16)
    const int vst = (kend16 <= 8) ? 128 : 256;        // V LDS row stride (shorts)

    const unsigned short* qb  = qkv + (size_t)(b * T_) * QS_ + h * DH_;
    const unsigned short* kb  = qb + D_;
    const unsigned short* vtb = Vt + (size_t)bh * DH_ * T_;

    // ---- stage K rows [0, kend16*16): round = 8 rows (1024 B), linear dest
    {
        const int nr = kend16 * 2;
        for (int rd = wave; rd < nr; rd += 8) {
            const int row = rd * 8 + (lane >> 3);
            const int c   = (lane & 7) ^ (row & 7);
            ASYNC16(kb + (size_t)row * QS_ + c * 8, &Klds[rd * 512]);
        }
    }
    // ---- stage V rows d=[0,64), cols [0,vst): round = 1024 B, linear dest
    if (vst == 256) {
        for (int rd = wave; rd < 32; rd += 8) {
            const int d = rd * 2 + (lane >> 5);
            const int c = (lane & 31) ^ (d & 7);
            ASYNC16(vtb + (size_t)d * T_ + c * 8, &Vlds[rd * 512]);
        }
    } else {
        for (int rd = wave; rd < 16; rd += 8) {
            const int d = rd * 4 + (lane >> 4);
            const int c = (lane & 15) ^ (d & 7);
            ASYNC16(vtb + (size_t)d * T_ + c * 8, &Vlds[rd * 512]);
        }
    }

    // hoist Q for both tiles while staging loads are in flight
    bf16x8 aqs[2][2];
#pragma unroll
    for (int i = 0; i < 2; ++i) {
        const int m0 = (i ? (15 - wave) : wave) * 16;
#pragma unroll
        for (int ks = 0; ks < 2; ++ks)
            aqs[i][ks] = *(const bf16x8*)(qb + (size_t)(m0 + lo) * QS_ + ks * 32 + hi * 8);
    }

    asm volatile("s_waitcnt vmcnt(0)" ::: "memory");
    __syncthreads();

#pragma unroll
    for (int i = 0; i < 2; ++i) {
        const int tq = i ? (15 - wave) : wave;
        const int m0 = tq * 16;
        const int qrow = m0 + lo;
        const int kmax  = min(m0 + 14, nt - 1);
        const int ktmax = kmax >> 4;

        f32x4 s[16] = {};
#pragma unroll
        for (int kt = 0; kt < 16; ++kt) {
            if (kt <= ktmax) {
#pragma unroll
                for (int ks = 0; ks < 2; ++ks) {
                    bf16x8 kf = *(const bf16x8*)&Klds[(kt * 16 + lo) * 64
                                                     + ((ks * 4 + hi) ^ lo7) * 8];
                    s[kt] = __builtin_amdgcn_mfma_f32_16x16x32_bf16(kf, aqs[i][ks], s[kt], 0, 0, 0);
                }
            }
        }

        float lsum = 0.f;
        s16x4 pf[16];
#pragma unroll
        for (int kt = 0; kt < 16; ++kt) {
            if (kt <= ktmax) {
#pragma unroll
                for (int r = 0; r < 4; ++r) {
                    const int key = kt * 16 + hi * 4 + r;
                    const bool valid = (key < qrow) && (key < nt);
                    const float p = valid ? __expf(s[kt][r] * 0.125f) : 0.f;
                    lsum += p;
                    pf[kt][r] = (short)f2bf(p);
                }
            }
        }

        f32x4 o[4] = {};
#pragma unroll
        for (int kt = 0; kt < 16; ++kt) {
            if (kt <= ktmax) {
#pragma unroll
                for (int nd = 0; nd < 4; ++nd) {
                    const int cidx = (kt * 2 + (hi >> 1)) ^ lo7;
                    s16x4 bv = *(const s16x4*)&Vlds[(nd * 16 + lo) * vst
                                                    + cidx * 8 + (hi & 1) * 4];
                    o[nd] = __builtin_amdgcn_mfma_f32_16x16x16bf16_1k(pf[kt], bv, o[nd], 0, 0, 0);
                }
            }
        }

        lsum += __shfl_xor(lsum, 16, 64);
        lsum += __shfl_xor(lsum, 32, 64);
        float linv[4];
#pragma unroll
        for (int r = 0; r < 4; ++r) {
            const float lq = __shfl(lsum, hi * 4 + r, 64);
            linv[r] = (lq > 0.f) ? (1.f / lq) : 0.f;
        }

#pragma unroll
        for (int nd = 0; nd < 4; ++nd) {
#pragma unroll
            for (int r = 0; r < 4; ++r) {
                ctx[((size_t)(b * T_ + m0 + hi * 4 + r)) * D_ + h * DH_ + nd * 16 + lo]
                    = f2bf(o[nd][r] * linv[r]);
            }
        }
    }
}
#else
// Fallback (never used on gfx950 harness): same launch geometry + signature
// (768 blocks x 512 threads), 8 waves x 2 balanced q-tiles, LDS P roundtrip.
__global__ __launch_bounds__(512) void attn_fused(
    const unsigned short* __restrict__ qkv, const unsigned short* __restrict__ Vt,
    const int* __restrict__ num_turns, unsigned short* __restrict__ ctx)
{
    __shared__ unsigned short Plds[8][16 * 264];   // 67.5 KB

    const int bh = blockIdx.x;
    const int b = bh / NH_;
    const int h = bh - b * NH_;
    const int tid = threadIdx.x;
    const int wave = tid >> 6;
    const int lane = tid & 63;
    const int hi = lane >> 4;
    const int lo = lane & 15;

    const int nt = num_turns[b];
    const unsigned short* qb = qkv + (size_t)(b * T_) * QS_ + h * DH_;
    const unsigned short* kb = qb + D_;
    const unsigned short* vtb = Vt + (size_t)bh * DH_ * T_;

    for (int ii = 0; ii < 2; ++ii) {
        const int m0 = (ii ? (15 - wave) : wave) * 16;
        const int kmax = min(m0 + 14, nt - 1);
        const int n0hi = (kmax >> 4) | 1;
        const int nks  = (kmax >> 5) + 1;

        bf16x8 aq[2];
#pragma unroll
        for (int ks = 0; ks < 2; ++ks)
            aq[ks] = *(const bf16x8*)(qb + (size_t)(m0 + lo) * QS_ + ks * 32 + hi * 8);

        f32x4 s[16] = {};
#pragma unroll
        for (int n0 = 0; n0 < 16; ++n0) {
            if (n0 <= n0hi) {
#pragma unroll
                for (int ks = 0; ks < 2; ++ks) {
                    bf16x8 bk = *(const bf16x8*)(kb + (size_t)(n0 * 16 + lo) * QS_ + ks * 32 + hi * 8);
                    s[n0] = __builtin_amdgcn_mfma_f32_16x16x32_bf16(aq[ks], bk, s[n0], 0, 0, 0);
                }
            }
        }

#pragma unroll
        for (int r = 0; r < 4; ++r) {
            const int qrow = m0 + hi * 4 + r;
            float mr = -1e30f;
#pragma unroll
            for (int n0 = 0; n0 < 16; ++n0) {
                if (n0 <= n0hi) {
                    int key = n0 * 16 + lo;
                    bool valid = (key < qrow) && (key < nt);
                    float se = valid ? s[n0][r] * 0.125f : -1e30f;
                    s[n0][r] = se;
                    mr = fmaxf(mr, se);
                }
            }
#pragma unroll
            for (int off = 1; off < 16; off <<= 1) mr = fmaxf(mr, __shfl_xor(mr, off, 64));

            float lr = 0.f;
#pragma unroll
            for (int n0 = 0; n0 < 16; ++n0) {
                if (n0 <= n0hi) {
                    float se = s[n0][r];
                    float pv = (se > -5e29f) ? __expf(se - mr) : 0.f;
                    s[n0][r] = pv;
                    lr += pv;
                }
            }
#pragma unroll
            for (int off = 1; off < 16; off <<= 1) lr += __shfl_xor(lr, off, 64);

            float inv = (lr > 0.f) ? (1.f / lr) : 0.f;
#pragma unroll
            for (int n0 = 0; n0 < 16; ++n0) {
                if (n0 <= n0hi) {
                    Plds[wave][(hi * 4 + r) * 264 + n0 * 16 + lo] = f2bf(s[n0][r] * inv);
                }
            }
        }

        f32x4 o[4] = {};
#pragma unroll
        for (int ks = 0; ks < 8; ++ks) {
            if (ks < nks) {
                const unsigned short* lp = &Plds[wave][lo * 264 + ks * 32 + hi * 8];
                bf16x8 ap = __builtin_bit_cast(bf16x8, *(const uint4*)lp);
#pragma unroll
                for (int nd = 0; nd < 4; ++nd) {
                    bf16x8 bvf = *(const bf16x8*)(vtb + (size_t)(nd * 16 + lo) * T_ + ks * 32 + hi * 8);
                    o[nd] = __builtin_amdgcn_mfma_f32_16x16x32_bf16(ap, bvf, o[nd], 0, 0, 0);
                }
            }
        }

#pragma unroll
        for (int nd = 0; nd < 4; ++nd) {
#pragma unroll
            for (int r = 0; r < 4; ++r) {
                ctx[((size_t)(b * T_ + m0 + hi * 4 + r)) * D_ + h * DH_ + nd * 16 + lo]
                    = f2bf(o[nd][r]);
            }
        }
    }
}
#endif

// ---------------------------------------------------------------------------
// Logits as skinny MFMA GEMM: M=16384, N=16 (7 used), K=1536 (Hb | ctxb).
// Second K-half uses pre-fused Wf = Wo@Wc2 (out-proj eliminated). R6 version.
// ---------------------------------------------------------------------------
#define WCP 1544

__global__ __launch_bounds__(256) void logits_mfma(
    const unsigned short* __restrict__ Hb, const unsigned short* __restrict__ ctxb,
    const float* __restrict__ Wc, const float* __restrict__ Wf,
    const float* __restrict__ bc, const float* __restrict__ boc,
    const int* __restrict__ num_turns, float* __restrict__ out)
{
    __shared__ unsigned short sW[16 * WCP];

    const int tid = threadIdx.x;
    const int wave = tid >> 6;
    const int lane = tid & 63;
    const int hi = lane >> 4;
    const int lo = lane & 15;

    for (int i = tid; i < 16 * 1536; i += 256) {
        int n = i & 15, kk = i >> 4;
        float val = 0.f;
        if (n < C_)
            val = (kk < D_) ? Wc[(size_t)kk * C_ + n] : Wf[(kk - D_) * C_ + n];
        sW[n * WCP + kk] = f2bf(val);
    }
    __syncthreads();

    const int m0 = blockIdx.x * 64 + wave * 16;
    const unsigned short* hrow = Hb   + (size_t)(m0 + lo) * D_;
    const unsigned short* crow = ctxb + (size_t)(m0 + lo) * D_;

    f32x4 acc = {};
#pragma unroll
    for (int kt = 0; kt < 24; ++kt) {
        bf16x8 a = *(const bf16x8*)(hrow + kt * 32 + hi * 8);
        bf16x8 w = *(const bf16x8*)&sW[lo * WCP + kt * 32 + hi * 8];
        acc = __builtin_amdgcn_mfma_f32_16x16x32_bf16(a, w, acc, 0, 0, 0);
    }
#pragma unroll
    for (int kt = 0; kt < 24; ++kt) {
        bf16x8 a = *(const bf16x8*)(crow + kt * 32 + hi * 8);
        bf16x8 w = *(const bf16x8*)&sW[lo * WCP + (768 + kt * 32) + hi * 8];
        acc = __builtin_amdgcn_mfma_f32_16x16x32_bf16(a, w, acc, 0, 0, 0);
    }

    if (lo < C_) {
        const float b0 = bc[lo];
        const float b1 = boc[lo];
#pragma unroll
        for (int r = 0; r < 4; ++r) {
            const int row = m0 + hi * 4 + r;
            const int t = row & (T_ - 1);
            const float tot = acc[r] + b0 + ((t != 0) ? b1 : 0.f);
            out[(size_t)row * C_ + lo] = tot;
            const int b = row >> 8;
            if (t == num_turns[b] - 1)
                out[(size_t)B_ * T_ * C_ + (size_t)b * C_ + lo] = tot;
        }
    }
}

// ---------------------------------------------------------------------------
extern "C" void kernel_launch(void* const* d_in, const int* in_sizes, int n_in,
                              void* d_out, int out_size, void* d_ws, size_t ws_size,
                              hipStream_t stream)
{
    const float* H  = (const float*)d_in[0];
    const float* Wq = (const float*)d_in[1];
    const float* bq = (const float*)d_in[2];
    const float* Wk = (const float*)d_in[3];
    const float* bk = (const float*)d_in[4];
    const float* Wv = (const float*)d_in[5];
    const float* bv = (const float*)d_in[6];
    const float* Wo = (const float*)d_in[7];
    const float* bo = (const float*)d_in[8];
    const float* Wc = (const float*)d_in[9];
    const float* bc = (const float*)d_in[10];
    const int* num_turns = (const int*)d_in[11];
    float* out = (float*)d_out;

    const int M = B_ * T_;                       // 16384
    const size_t per = (size_t)M * D_;           // 12,582,912
    const size_t wsz = (size_t)D_ * D_;

    unsigned short* ws16 = (unsigned short*)d_ws;
    unsigned short* Hb    = ws16;                         // per
    unsigned short* Wqkvt = Hb + per;                     // 3*wsz
    unsigned short* qkvb  = Wqkvt + 3 * wsz;              // M*2304 (v region unused)
    unsigned short* ctxb  = qkvb + (size_t)M * QS_;       // per
    unsigned short* Vtb   = ctxb + per;                   // per (V transposed)
    float* bqkv = (float*)(Vtb + per);                    // 2304 f32
    float* Wf   = bqkv + QS_;                             // 768*7 f32
    float* boc  = Wf + (size_t)D_ * C_;                   // 7 f32

    // 1) fused prologue (Wf first, then bias/transpose/conv)
    prologue<<<PRO_ALL, 256, 0, stream>>>(H, Hb, Wq, Wk, Wv, Wqkvt,
                                          bq, bk, bv, bqkv,
                                          Wo, Wc, bo, Wf, boc);

    // 2) 8-phase 256x256 qkv projection (v -> Vt transposed; dead-wave skip)
    dim3 qkvGrid(9, 64);                         // 576 blocks = 8 xcd * 72
    gemm_qkv_8ph<<<qkvGrid, 512, 0, stream>>>(Hb, Wqkvt, bqkv, qkvb,
                                              Vtb, num_turns);

    // 3) attention — UNCONDITIONAL launch config (host pass can't see device
    //    builtins; both kernel variants expect 768 blocks x 512 threads)
    attn_fused<<<B_ * NH_, 512, 0, stream>>>(qkvb, Vtb, num_turns, ctxb);

    // 4) logits skinny GEMM (out-proj folded in) + final gather
    logits_mfma<<<M / 64, 256, 0, stream>>>(Hb, ctxb, Wc, Wf, bc, boc,
                                            num_turns, out);
}

// Round 12
// 223.190 us; speedup vs baseline: 1.1816x; 1.1816x over previous
//
#include <hip/hip_runtime.h>
#include <hip/hip_bf16.h>

#define B_  64
#define T_  256
#define D_  768
#define NH_ 12
#define DH_ 64
#define C_  7
#define QS_ 2304            // qkv fused row stride (3*D)

using f32x4  = __attribute__((ext_vector_type(4))) float;
using bf16x8 = __attribute__((ext_vector_type(8))) __bf16;
using u16x8  = __attribute__((ext_vector_type(8))) unsigned short;
using u16x4  = __attribute__((ext_vector_type(4))) unsigned short;
using s16x4  = __attribute__((ext_vector_type(4))) short;

#if defined(__has_builtin)
#if __has_builtin(__builtin_amdgcn_mfma_f32_16x16x16bf16_1k)
#define HAS_MFMA16 1
#endif
#endif
// NOTE: HAS_MFMA16 differs between host and device compile passes (host pass
// can't see amdgcn builtins). Launch config and kernel signatures MUST be
// identical in both branches — R3/R4 failed on exactly this.

static __device__ inline unsigned short f2bf(float f) {
    union { float f; unsigned u; } c; c.f = f;
    unsigned u = c.u;
    return (unsigned short)((u + 0x7fffu + ((u >> 16) & 1u)) >> 16);
}

// async global->LDS, 16 bytes per lane (wave-uniform LDS base + lane*16)
#define ASYNC16(gp, lp) __builtin_amdgcn_global_load_lds(                      \
    (const __attribute__((address_space(1))) unsigned int*)(gp),               \
    (__attribute__((address_space(3))) unsigned int*)(lp), 16, 0, 0)

// ---------------------------------------------------------------------------
// Fused prologue (one launch): flat grid. Slow serial blocks (Wf = Wo@Wc2)
// FIRST so they overlap the 6144 conv blocks instead of tailing.
//   [0,13)      : Wo@Wc2 -> Wcb[c][768+d] bf16 (+ boc = bo@Wc2)
//   [13,109)    : Wcb Wc1-half + zero padding (disjoint from WF writes)
//   [109,118)   : concat qkv bias
//   [118,1846)  : 3x weight transpose f32->bf16 (Wq,Wk,Wv)
//   [1846,7990) : H f32 -> bf16
// Wcb layout [16][1536] bf16: row n (= class col), col kk (= feature).
//   kk<768 -> Wc1[kk][n];  kk>=768 -> (Wo@Wc2)[kk-768][n];  n>=7 -> 0.
// ---------------------------------------------------------------------------
#define PRO_WF   13
#define PRO_WCB  96             // 16*1536/256
#define PRO_BIAS 9
#define PRO_TR   1728           // 3 * 576
#define PRO_CONV 6144
#define PRO_ALL  (PRO_WF + PRO_WCB + PRO_BIAS + PRO_TR + PRO_CONV)

__global__ __launch_bounds__(256) void prologue(
    const float* __restrict__ H, unsigned short* __restrict__ Hb,
    const float* __restrict__ Wq, const float* __restrict__ Wk,
    const float* __restrict__ Wv,
    unsigned short* __restrict__ Wqkvt,
    const float* __restrict__ bq, const float* __restrict__ bk,
    const float* __restrict__ bv, float* __restrict__ bqkv,
    const float* __restrict__ Wo, const float* __restrict__ Wc,
    const float* __restrict__ bo,
    unsigned short* __restrict__ Wcb, float* __restrict__ boc)
{
    __shared__ float tile[32][33];
    __shared__ float wcs[D_ * C_];          // Wc2 staged f32 (21.5 KB)
    const int blk = blockIdx.x;
    const int tid = threadIdx.x;

    if (blk < PRO_WF) {
        const int fb = blk;                  // 0..12
        for (int i = tid; i < D_ * C_; i += 256)
            wcs[i] = Wc[(size_t)D_ * C_ + i];
        __syncthreads();
        if (fb < 12) {
            const int dl = tid >> 2;
            const int ks = tid & 3;
            const int d  = fb * 64 + dl;
            const float* wrow = Wo + (size_t)d * D_;
            float a[C_] = {};
            for (int e = ks * 192; e < ks * 192 + 192; ++e) {
                const float w = wrow[e];
#pragma unroll
                for (int c = 0; c < C_; ++c) a[c] += w * wcs[e * C_ + c];
            }
#pragma unroll
            for (int c = 0; c < C_; ++c) {
                a[c] += __shfl_xor(a[c], 1, 64);
                a[c] += __shfl_xor(a[c], 2, 64);
            }
            if (ks == 0) {
#pragma unroll
                for (int c = 0; c < C_; ++c)
                    Wcb[c * 1536 + 768 + d] = f2bf(a[c]);
            }
        } else if (tid < C_) {
            float a = 0.f;
            for (int e = 0; e < D_; ++e) a += bo[e] * wcs[e * C_ + tid];
            boc[tid] = a;
        }
    } else if (blk < PRO_WF + PRO_WCB) {
        const int i  = (blk - PRO_WF) * 256 + tid;   // [0, 24576)
        const int n  = i / 1536;
        const int kk = i - n * 1536;
        if (kk < 768)       Wcb[i] = (n < C_) ? f2bf(Wc[(size_t)kk * C_ + n]) : 0;
        else if (n >= C_)   Wcb[i] = 0;
        // (n < 7, kk >= 768) written by the WF blocks — disjoint, no race.
    } else if (blk < PRO_WF + PRO_WCB + PRO_BIAS) {
        const int i = (blk - PRO_WF - PRO_WCB) * 256 + tid;
        if (i < D_)          bqkv[i] = bq[i];
        else if (i < 2 * D_) bqkv[i] = bk[i - D_];
        else if (i < 3 * D_) bqkv[i] = bv[i - 2 * D_];
    } else if (blk < PRO_WF + PRO_WCB + PRO_BIAS + PRO_TR) {
        const int tb = blk - PRO_WF - PRO_WCB - PRO_BIAS;
        const int z = tb / 576;             // 0..2 (Wq,Wk,Wv)
        const int rem = tb - z * 576;
        const int bx = (rem % 24) * 32;
        const int by = (rem / 24) * 32;
        const size_t wsz = (size_t)D_ * D_;
        const float* W = (z == 0) ? Wq : (z == 1) ? Wk : Wv;
        unsigned short* Wt = Wqkvt + (size_t)z * wsz;
        const int tx = tid & 31;
        const int ty = tid >> 5;
#pragma unroll
        for (int i = ty; i < 32; i += 8)
            tile[i][tx] = W[(size_t)(by + i) * D_ + bx + tx];
        __syncthreads();
#pragma unroll
        for (int i = ty; i < 32; i += 8)
            Wt[(size_t)(bx + i) * D_ + by + tx] = f2bf(tile[tx][i]);
    } else {
        const int i = ((blk - PRO_WF - PRO_WCB - PRO_BIAS - PRO_TR) * 256 + tid) * 8;
        float4 f0 = *(const float4*)(H + i);
        float4 f1 = *(const float4*)(H + i + 4);
        u16x8 u;
        u[0] = f2bf(f0.x); u[1] = f2bf(f0.y); u[2] = f2bf(f0.z); u[3] = f2bf(f0.w);
        u[4] = f2bf(f1.x); u[5] = f2bf(f1.y); u[6] = f2bf(f1.z); u[7] = f2bf(f1.w);
        *(uint4*)(Hb + i) = __builtin_bit_cast(uint4, u);
    }
}

// ---------------------------------------------------------------------------
// qkv projection: double-buffered counted-vmcnt bf16 MFMA GEMM, 512 threads.
// (byte-identical to the R9-verified kernel, 63.8 µs / MfmaUtil 29%.
//  R10's 8-phase 256^2 port regressed to 76 µs — at K=768 / 12 K-tiles the
//  deep pipeline never amortizes its 8 barriers/K-tile; structure closed.)
// ---------------------------------------------------------------------------
#define QBM 128
#define QBN 128
#define QBK 64
#define KQ  768
#define NKT 12

#define BAR   do { __builtin_amdgcn_s_barrier();                               \
                   __builtin_amdgcn_sched_barrier(0); } while (0)
#define VMW(n) do { asm volatile("s_waitcnt vmcnt(" #n ")" ::: "memory");      \
                    __builtin_amdgcn_sched_barrier(0); } while (0)

__global__ __launch_bounds__(512, 2) void gemm_qkv_db(
    const unsigned short* __restrict__ A,    // Hb [16384][768]
    const unsigned short* __restrict__ Bt,   // Wqkvt [2304][768]
    const float* __restrict__ bias,          // bqkv [2304]
    unsigned short* __restrict__ qkvb,       // [16384][2304] (q,k cols)
    unsigned short* __restrict__ Vt,         // [bh][d][t]
    const int* __restrict__ num_turns)
{
    __shared__ unsigned short As[2][QBM * QBK];   // 32 KB
    __shared__ unsigned short Bs[2][QBN * QBK];   // 32 KB

    const int tid = threadIdx.x;
    const int wid = tid >> 6;
    const int ln  = tid & 63;
    const int hi  = ln >> 4;
    const int lo  = ln & 15;
    const int wm  = (wid & 3) * 32;      // 4 M-groups of 32 rows
    const int wn  = (wid >> 2) * 64;     // 2 N-groups of 64 cols

    // XCD-aware remap: 2304 blocks = 8 xcd * 288 contiguous tiles
    const int L   = blockIdx.y * gridDim.x + blockIdx.x;   // grid (18,128)
    const int wg  = (L & 7) * 288 + (L >> 3);
    const int my  = wg / 18;
    const int nx  = wg - my * 18;

    const int row0 = my * QBM;
    const int col0 = nx * QBN;

    // dead-tile skip: k/v cols, rows t in [128,256), short dialogue
    if (col0 >= D_ && (row0 & (T_ - 1)) != 0) {
        if (num_turns[row0 >> 8] <= 128) return;
    }

    // staging addressing: thread covers rows (tid>>3) and (tid>>3)+64
    const int s0 = tid >> 3;
    const int ch = (tid & 7) ^ (s0 & 7);
    const unsigned short* a0 = A  + (size_t)(row0 + s0) * KQ + ch * 8;
    const unsigned short* b0 = Bt + (size_t)(col0 + s0) * KQ + ch * 8;

#define STG(t, q) do {                                                         \
    _Pragma("unroll") for (int c = 0; c < 2; ++c) {                            \
        ASYNC16(a0 + (size_t)(t) * QBK + (size_t)c * 64 * KQ,                  \
                &As[q][c * 4096 + wid * 512]);                                 \
        ASYNC16(b0 + (size_t)(t) * QBK + (size_t)c * 64 * KQ,                  \
                &Bs[q][c * 4096 + wid * 512]);                                 \
    }                                                                          \
} while (0)

    const int fcs[2] = { (0 * 4 + hi) ^ (lo & 7), (1 * 4 + hi) ^ (lo & 7) };

    f32x4 acc[2][4] = {};

#define TILE(t, q, qn) do {                                                    \
    if ((t) + 1 < NKT) { STG((t) + 1, qn); VMW(4); }                           \
    else               { VMW(0); }                                             \
    BAR;                                                                       \
    _Pragma("unroll") for (int s = 0; s < 2; ++s) {                            \
        const int fc = fcs[s];                                                 \
        bf16x8 af[2], bfr[4];                                                  \
        _Pragma("unroll") for (int i = 0; i < 2; ++i)                          \
            af[i] = *(const bf16x8*)&As[q][(wm + i * 16 + lo) * QBK + fc * 8]; \
        _Pragma("unroll") for (int j = 0; j < 4; ++j)                          \
            bfr[j] = *(const bf16x8*)&Bs[q][(wn + j * 16 + lo) * QBK + fc * 8];\
        __builtin_amdgcn_s_setprio(1);                                         \
        _Pragma("unroll") for (int i = 0; i < 2; ++i)                          \
        _Pragma("unroll") for (int j = 0; j < 4; ++j)                          \
            acc[i][j] = __builtin_amdgcn_mfma_f32_16x16x32_bf16(               \
                af[i], bfr[j], acc[i][j], 0, 0, 0);                            \
        __builtin_amdgcn_s_setprio(0);                                         \
    }                                                                          \
    BAR;                                                                       \
} while (0)

    STG(0, 0);
#pragma unroll
    for (int g = 0; g < NKT; g += 2) {
        TILE(g + 0, 0, 1);
        TILE(g + 1, 1, 0);
    }
#undef STG
#undef TILE

    // ---- C write ----
    const int bidx = row0 >> 8;
    const int t0   = row0 & (T_ - 1);
    if (col0 >= 1536) {
        // v tile -> Vt[bh][d][t], 8B packed stores (4 consecutive t per store)
#pragma unroll
        for (int j = 0; j < 4; ++j) {
            const int dcol = (col0 - 1536) + wn + j * 16 + lo;   // [0,768)
            const float bcol = bias[col0 + wn + j * 16 + lo];
            unsigned short* vrow =
                Vt + ((size_t)(bidx * NH_ + (dcol >> 6)) * DH_ + (dcol & 63)) * T_ + t0;
#pragma unroll
            for (int i = 0; i < 2; ++i) {
                u16x4 pk;
#pragma unroll
                for (int r = 0; r < 4; ++r) pk[r] = f2bf(acc[i][j][r] + bcol);
                *(u16x4*)(vrow + wm + i * 16 + hi * 4) = pk;
            }
        }
        return;
    }
#pragma unroll
    for (int j = 0; j < 4; ++j) {
        const int col = col0 + wn + j * 16 + lo;
        const float bcol = bias[col];
#pragma unroll
        for (int i = 0; i < 2; ++i) {
#pragma unroll
            for (int r = 0; r < 4; ++r) {
                const int row = row0 + wm + i * 16 + hi * 4 + r;
                qkvb[(size_t)row * QS_ + col] = f2bf(acc[i][j][r] + bcol);
            }
        }
    }
}

// ---------------------------------------------------------------------------
// Fused MFMA flash attention, block-per-bh, 512 threads (8 waves x 2 balanced
// q-tiles {w, 15-w}). LAUNCH CONFIG IDENTICAL FOR BOTH COMPILE BRANCHES
// (<<<768, 512>>>). K/V staged via ASYNC global_load_lds with PRE-SWIZZLED
// per-lane global source + linear LDS dest (verified R8).
// ---------------------------------------------------------------------------
#if HAS_MFMA16
__global__ __launch_bounds__(512) void attn_fused(
    const unsigned short* __restrict__ qkv, const unsigned short* __restrict__ Vt,
    const int* __restrict__ num_turns, unsigned short* __restrict__ ctx)
{
    __shared__ unsigned short Klds[256 * 64];   // 32 KB
    __shared__ unsigned short Vlds[64 * 256];   // 32 KB (row stride vst shorts)

    const int bh = blockIdx.x;
    const int b = bh / NH_;
    const int h = bh - b * NH_;
    const int tid = threadIdx.x;
    const int wave = tid >> 6;
    const int lane = tid & 63;
    const int hi = lane >> 4;
    const int lo = lane & 15;
    const int lo7 = lo & 7;

    const int nt = num_turns[b];
    const int kend16 = (min(254, nt - 1) >> 4) + 1;   // staged K tiles (1..16)
    const int vst = (kend16 <= 8) ? 128 : 256;        // V LDS row stride (shorts)

    const unsigned short* qb  = qkv + (size_t)(b * T_) * QS_ + h * DH_;
    const unsigned short* kb  = qb + D_;
    const unsigned short* vtb = Vt + (size_t)bh * DH_ * T_;

    // ---- stage K rows [0, kend16*16): round = 8 rows (1024 B), linear dest
    {
        const int nr = kend16 * 2;
        for (int rd = wave; rd < nr; rd += 8) {
            const int row = rd * 8 + (lane >> 3);
            const int c   = (lane & 7) ^ (row & 7);
            ASYNC16(kb + (size_t)row * QS_ + c * 8, &Klds[rd * 512]);
        }
    }
    // ---- stage V rows d=[0,64), cols [0,vst): round = 1024 B, linear dest
    if (vst == 256) {
        for (int rd = wave; rd < 32; rd += 8) {
            const int d = rd * 2 + (lane >> 5);
            const int c = (lane & 31) ^ (d & 7);
            ASYNC16(vtb + (size_t)d * T_ + c * 8, &Vlds[rd * 512]);
        }
    } else {
        for (int rd = wave; rd < 16; rd += 8) {
            const int d = rd * 4 + (lane >> 4);
            const int c = (lane & 15) ^ (d & 7);
            ASYNC16(vtb + (size_t)d * T_ + c * 8, &Vlds[rd * 512]);
        }
    }

    // hoist Q for both tiles while staging loads are in flight
    bf16x8 aqs[2][2];
#pragma unroll
    for (int i = 0; i < 2; ++i) {
        const int m0 = (i ? (15 - wave) : wave) * 16;
#pragma unroll
        for (int ks = 0; ks < 2; ++ks)
            aqs[i][ks] = *(const bf16x8*)(qb + (size_t)(m0 + lo) * QS_ + ks * 32 + hi * 8);
    }

    asm volatile("s_waitcnt vmcnt(0)" ::: "memory");
    __syncthreads();

#pragma unroll
    for (int i = 0; i < 2; ++i) {
        const int tq = i ? (15 - wave) : wave;
        const int m0 = tq * 16;
        const int qrow = m0 + lo;
        const int kmax  = min(m0 + 14, nt - 1);
        const int ktmax = kmax >> 4;

        f32x4 s[16] = {};
#pragma unroll
        for (int kt = 0; kt < 16; ++kt) {
            if (kt <= ktmax) {
#pragma unroll
                for (int ks = 0; ks < 2; ++ks) {
                    bf16x8 kf = *(const bf16x8*)&Klds[(kt * 16 + lo) * 64
                                                     + ((ks * 4 + hi) ^ lo7) * 8];
                    s[kt] = __builtin_amdgcn_mfma_f32_16x16x32_bf16(kf, aqs[i][ks], s[kt], 0, 0, 0);
                }
            }
        }

        float lsum = 0.f;
        s16x4 pf[16];
#pragma unroll
        for (int kt = 0; kt < 16; ++kt) {
            if (kt <= ktmax) {
#pragma unroll
                for (int r = 0; r < 4; ++r) {
                    const int key = kt * 16 + hi * 4 + r;
                    const bool valid = (key < qrow) && (key < nt);
                    const float p = valid ? __expf(s[kt][r] * 0.125f) : 0.f;
                    lsum += p;
                    pf[kt][r] = (short)f2bf(p);
                }
            }
        }

        f32x4 o[4] = {};
#pragma unroll
        for (int kt = 0; kt < 16; ++kt) {
            if (kt <= ktmax) {
#pragma unroll
                for (int nd = 0; nd < 4; ++nd) {
                    const int cidx = (kt * 2 + (hi >> 1)) ^ lo7;
                    s16x4 bv = *(const s16x4*)&Vlds[(nd * 16 + lo) * vst
                                                    + cidx * 8 + (hi & 1) * 4];
                    o[nd] = __builtin_amdgcn_mfma_f32_16x16x16bf16_1k(pf[kt], bv, o[nd], 0, 0, 0);
                }
            }
        }

        lsum += __shfl_xor(lsum, 16, 64);
        lsum += __shfl_xor(lsum, 32, 64);
        float linv[4];
#pragma unroll
        for (int r = 0; r < 4; ++r) {
            const float lq = __shfl(lsum, hi * 4 + r, 64);
            linv[r] = (lq > 0.f) ? (1.f / lq) : 0.f;
        }

#pragma unroll
        for (int nd = 0; nd < 4; ++nd) {
#pragma unroll
            for (int r = 0; r < 4; ++r) {
                ctx[((size_t)(b * T_ + m0 + hi * 4 + r)) * D_ + h * DH_ + nd * 16 + lo]
                    = f2bf(o[nd][r] * linv[r]);
            }
        }
    }
}
#else
// Fallback (never used on gfx950 harness): same launch geometry + signature
// (768 blocks x 512 threads), 8 waves x 2 balanced q-tiles, LDS P roundtrip.
__global__ __launch_bounds__(512) void attn_fused(
    const unsigned short* __restrict__ qkv, const unsigned short* __restrict__ Vt,
    const int* __restrict__ num_turns, unsigned short* __restrict__ ctx)
{
    __shared__ unsigned short Plds[8][16 * 264];   // 67.5 KB

    const int bh = blockIdx.x;
    const int b = bh / NH_;
    const int h = bh - b * NH_;
    const int tid = threadIdx.x;
    const int wave = tid >> 6;
    const int lane = tid & 63;
    const int hi = lane >> 4;
    const int lo = lane & 15;

    const int nt = num_turns[b];
    const unsigned short* qb = qkv + (size_t)(b * T_) * QS_ + h * DH_;
    const unsigned short* kb = qb + D_;
    const unsigned short* vtb = Vt + (size_t)bh * DH_ * T_;

    for (int ii = 0; ii < 2; ++ii) {
        const int m0 = (ii ? (15 - wave) : wave) * 16;
        const int kmax = min(m0 + 14, nt - 1);
        const int n0hi = (kmax >> 4) | 1;
        const int nks  = (kmax >> 5) + 1;

        bf16x8 aq[2];
#pragma unroll
        for (int ks = 0; ks < 2; ++ks)
            aq[ks] = *(const bf16x8*)(qb + (size_t)(m0 + lo) * QS_ + ks * 32 + hi * 8);

        f32x4 s[16] = {};
#pragma unroll
        for (int n0 = 0; n0 < 16; ++n0) {
            if (n0 <= n0hi) {
#pragma unroll
                for (int ks = 0; ks < 2; ++ks) {
                    bf16x8 bk = *(const bf16x8*)(kb + (size_t)(n0 * 16 + lo) * QS_ + ks * 32 + hi * 8);
                    s[n0] = __builtin_amdgcn_mfma_f32_16x16x32_bf16(aq[ks], bk, s[n0], 0, 0, 0);
                }
            }
        }

#pragma unroll
        for (int r = 0; r < 4; ++r) {
            const int qrow = m0 + hi * 4 + r;
            float mr = -1e30f;
#pragma unroll
            for (int n0 = 0; n0 < 16; ++n0) {
                if (n0 <= n0hi) {
                    int key = n0 * 16 + lo;
                    bool valid = (key < qrow) && (key < nt);
                    float se = valid ? s[n0][r] * 0.125f : -1e30f;
                    s[n0][r] = se;
                    mr = fmaxf(mr, se);
                }
            }
#pragma unroll
            for (int off = 1; off < 16; off <<= 1) mr = fmaxf(mr, __shfl_xor(mr, off, 64));

            float lr = 0.f;
#pragma unroll
            for (int n0 = 0; n0 < 16; ++n0) {
                if (n0 <= n0hi) {
                    float se = s[n0][r];
                    float pv = (se > -5e29f) ? __expf(se - mr) : 0.f;
                    s[n0][r] = pv;
                    lr += pv;
                }
            }
#pragma unroll
            for (int off = 1; off < 16; off <<= 1) lr += __shfl_xor(lr, off, 64);

            float inv = (lr > 0.f) ? (1.f / lr) : 0.f;
#pragma unroll
            for (int n0 = 0; n0 < 16; ++n0) {
                if (n0 <= n0hi) {
                    Plds[wave][(hi * 4 + r) * 264 + n0 * 16 + lo] = f2bf(s[n0][r] * inv);
                }
            }
        }

        f32x4 o[4] = {};
#pragma unroll
        for (int ks = 0; ks < 8; ++ks) {
            if (ks < nks) {
                const unsigned short* lp = &Plds[wave][lo * 264 + ks * 32 + hi * 8];
                bf16x8 ap = __builtin_bit_cast(bf16x8, *(const uint4*)lp);
#pragma unroll
                for (int nd = 0; nd < 4; ++nd) {
                    bf16x8 bvf = *(const bf16x8*)(vtb + (size_t)(nd * 16 + lo) * T_ + ks * 32 + hi * 8);
                    o[nd] = __builtin_amdgcn_mfma_f32_16x16x32_bf16(ap, bvf, o[nd], 0, 0, 0);
                }
            }
        }

#pragma unroll
        for (int nd = 0; nd < 4; ++nd) {
#pragma unroll
            for (int r = 0; r < 4; ++r) {
                ctx[((size_t)(b * T_ + m0 + hi * 4 + r)) * D_ + h * DH_ + nd * 16 + lo]
                    = f2bf(o[nd][r]);
            }
        }
    }
}
#endif

// ---------------------------------------------------------------------------
// Logits skinny MFMA GEMM: M=16384, N=16 (7 used), K=1536 (Hb | ctxb).
// Weights come from the PREBUILT global bf16 table Wcb[16][1536] (48 KB,
// L2-resident) — no LDS staging, no barrier, no per-block rebuild.
// Layout identical to the old sW: w-frag = Wcb[lo*1536 + kk].
// ---------------------------------------------------------------------------
__global__ __launch_bounds__(256) void logits_mfma(
    const unsigned short* __restrict__ Hb, const unsigned short* __restrict__ ctxb,
    const unsigned short* __restrict__ Wcb,
    const float* __restrict__ bc, const float* __restrict__ boc,
    const int* __restrict__ num_turns, float* __restrict__ out)
{
    const int tid = threadIdx.x;
    const int wave = tid >> 6;
    const int lane = tid & 63;
    const int hi = lane >> 4;
    const int lo = lane & 15;

    const int m0 = blockIdx.x * 64 + wave * 16;
    const unsigned short* hrow = Hb   + (size_t)(m0 + lo) * D_;
    const unsigned short* crow = ctxb + (size_t)(m0 + lo) * D_;
    const unsigned short* wrow = Wcb  + (size_t)lo * 1536;

    f32x4 acc = {};
#pragma unroll
    for (int kt = 0; kt < 24; ++kt) {
        bf16x8 a = *(const bf16x8*)(hrow + kt * 32 + hi * 8);
        bf16x8 w = *(const bf16x8*)(wrow + kt * 32 + hi * 8);
        acc = __builtin_amdgcn_mfma_f32_16x16x32_bf16(a, w, acc, 0, 0, 0);
    }
#pragma unroll
    for (int kt = 0; kt < 24; ++kt) {
        bf16x8 a = *(const bf16x8*)(crow + kt * 32 + hi * 8);
        bf16x8 w = *(const bf16x8*)(wrow + 768 + kt * 32 + hi * 8);
        acc = __builtin_amdgcn_mfma_f32_16x16x32_bf16(a, w, acc, 0, 0, 0);
    }

    if (lo < C_) {
        const float b0 = bc[lo];
        const float b1 = boc[lo];
#pragma unroll
        for (int r = 0; r < 4; ++r) {
            const int row = m0 + hi * 4 + r;
            const int t = row & (T_ - 1);
            const float tot = acc[r] + b0 + ((t != 0) ? b1 : 0.f);
            out[(size_t)row * C_ + lo] = tot;
            const int b = row >> 8;
            if (t == num_turns[b] - 1)
                out[(size_t)B_ * T_ * C_ + (size_t)b * C_ + lo] = tot;
        }
    }
}

// ---------------------------------------------------------------------------
extern "C" void kernel_launch(void* const* d_in, const int* in_sizes, int n_in,
                              void* d_out, int out_size, void* d_ws, size_t ws_size,
                              hipStream_t stream)
{
    const float* H  = (const float*)d_in[0];
    const float* Wq = (const float*)d_in[1];
    const float* bq = (const float*)d_in[2];
    const float* Wk = (const float*)d_in[3];
    const float* bk = (const float*)d_in[4];
    const float* Wv = (const float*)d_in[5];
    const float* bv = (const float*)d_in[6];
    const float* Wo = (const float*)d_in[7];
    const float* bo = (const float*)d_in[8];
    const float* Wc = (const float*)d_in[9];
    const float* bc = (const float*)d_in[10];
    const int* num_turns = (const int*)d_in[11];
    float* out = (float*)d_out;

    const int M = B_ * T_;                       // 16384
    const size_t per = (size_t)M * D_;           // 12,582,912
    const size_t wsz = (size_t)D_ * D_;

    unsigned short* ws16 = (unsigned short*)d_ws;
    unsigned short* Hb    = ws16;                         // per
    unsigned short* Wqkvt = Hb + per;                     // 3*wsz
    unsigned short* qkvb  = Wqkvt + 3 * wsz;              // M*2304 (v region unused)
    unsigned short* ctxb  = qkvb + (size_t)M * QS_;       // per
    unsigned short* Vtb   = ctxb + per;                   // per (V transposed)
    float* bqkv = (float*)(Vtb + per);                    // 2304 f32
    float* boc  = bqkv + QS_;                             // 8 f32
    unsigned short* Wcb = (unsigned short*)(boc + 8);     // 16*1536 bf16

    // 1) fused prologue (Wf/Wcb first, then bias/transpose/conv)
    prologue<<<PRO_ALL, 256, 0, stream>>>(H, Hb, Wq, Wk, Wv, Wqkvt,
                                          bq, bk, bv, bqkv,
                                          Wo, Wc, bo, Wcb, boc);

    // 2) double-buffered qkv projection, 512 thr / 8 waves (16 waves/CU)
    dim3 qkvGrid(18, 128);                       // 2304 blocks, 2/CU resident
    gemm_qkv_db<<<qkvGrid, 512, 0, stream>>>(Hb, Wqkvt, bqkv, qkvb,
                                             Vtb, num_turns);

    // 3) attention — UNCONDITIONAL launch config (host pass can't see device
    //    builtins; both kernel variants expect 768 blocks x 512 threads)
    attn_fused<<<B_ * NH_, 512, 0, stream>>>(qkvb, Vtb, num_turns, ctxb);

    // 4) logits skinny GEMM (prebuilt global weight table) + final gather
    logits_mfma<<<M / 64, 256, 0, stream>>>(Hb, ctxb, Wcb, bc, boc,
                                            num_turns, out);
}